// Round 4
// baseline (2095.904 us; speedup 1.0000x reference)
//
#include <hip/hip_runtime.h>
#include <hip/hip_bf16.h>
#include <hip/hip_fp8.h>
#include <cstdint>
#include <cstddef>

// Problem constants (from reference)
#define E_ 8
#define H_ 2048
#define I_ 5632
#define N1_ (2 * I_)
#define G_ 128
#define T_ 256
#define RPE 256            // fixed rows per expert (= T_, exact worst case)
#define SLOTS (E_ * RPE)   // 2048

typedef __attribute__((ext_vector_type(4))) float f32x4;
typedef __attribute__((ext_vector_type(8))) __bf16 bf16x8;

// Workspace layout (bytes). Total ~31.5 MB.
#define WS_CNT 0
#define WS_TOKEN 64
#define WS_GATE (64 + SLOTS * 4)
#define WS_A1 32768                    // SLOTS * H_ bf16 = 8 MB
#define WS_A2 (WS_A1 + SLOTS * H_ * 2) // SLOTS * I_ bf16 = 23 MB

__device__ __forceinline__ uint32_t pack_bf16x2(float a, float b) {
  union { float f; uint32_t u; } ua, ub;
  ua.f = a; ub.f = b;
  uint32_t ra = (ua.u + 0x7FFFu + ((ua.u >> 16) & 1u)) >> 16;         // RTNE bf16, low
  uint32_t rb = (ub.u + 0x7FFFu + ((ub.u >> 16) & 1u)) & 0xFFFF0000u; // high
  return ra | rb;
}

__device__ __forceinline__ float fp8_qdq1(float x) {
  x = fminf(fmaxf(x, -448.0f), 448.0f);
  __hip_fp8_e4m3 q(x);  // OCP e4m3fn on gfx950
  return (float)q;
}

// ---------------- routing: softmax top-2 -> fixed-capacity slot lists -------
__global__ void routing_kernel(const float* __restrict__ logits,
                               int* __restrict__ cnt,
                               int* __restrict__ token_of, float* __restrict__ gate_of) {
  __shared__ int s_cnt[E_];
  int t = threadIdx.x;  // one thread per token; blockDim.x == T_ == 256
  if (t < E_) s_cnt[t] = 0;
  __syncthreads();
  float l[E_];
#pragma unroll
  for (int e = 0; e < E_; e++) l[e] = logits[t * E_ + e];
  int i0 = 0;
#pragma unroll
  for (int e = 1; e < E_; e++) if (l[e] > l[i0]) i0 = e;  // ties -> lower idx
  int i1 = (i0 == 0) ? 1 : 0;
#pragma unroll
  for (int e = 0; e < E_; e++) if (e != i0 && l[e] > l[i1]) i1 = e;
  float g0 = 1.0f / (1.0f + expf(l[i1] - l[i0]));  // renormalized top-2 gates
  float g1 = 1.0f - g0;
  int s0 = atomicAdd(&s_cnt[i0], 1);
  int s1 = atomicAdd(&s_cnt[i1], 1);
  token_of[i0 * RPE + s0] = t;  gate_of[i0 * RPE + s0] = g0;
  token_of[i1 * RPE + s1] = t;  gate_of[i1 * RPE + s1] = g1;
  __syncthreads();
  if (t < E_) cnt[t] = s_cnt[t];
  for (int idx = t; idx < SLOTS; idx += 256) {
    int e = idx >> 8, r = idx & (RPE - 1);
    if (r >= s_cnt[e]) { token_of[idx] = 0; gate_of[idx] = 0.0f; }
  }
}

// ---------------- gather + fp8 qdq -> A1 (bf16, zero-padded rows) -----------
__global__ void gather_kernel(const float* __restrict__ hidden,
                              const float* __restrict__ is1,
                              const int* __restrict__ cnt,
                              const int* __restrict__ token_of,
                              __hip_bfloat16* __restrict__ A1) {
  int sg = blockIdx.x;
  int e = sg >> 8, r = sg & (RPE - 1);
  bool pad = (r >= cnt[e]);
  uint4 u;
  if (pad) {
    u.x = u.y = u.z = u.w = 0u;
  } else {
    int t = token_of[sg];
    float s1 = is1[e];
    const float4* hp = (const float4*)(hidden + (size_t)t * H_ + threadIdx.x * 8);
    float4 x0 = hp[0], x1 = hp[1];
    float q0 = fp8_qdq1(x0.x / s1), q1 = fp8_qdq1(x0.y / s1);
    float q2 = fp8_qdq1(x0.z / s1), q3 = fp8_qdq1(x0.w / s1);
    float q4 = fp8_qdq1(x1.x / s1), q5 = fp8_qdq1(x1.y / s1);
    float q6 = fp8_qdq1(x1.z / s1), q7 = fp8_qdq1(x1.w / s1);
    u.x = pack_bf16x2(q0, q1); u.y = pack_bf16x2(q2, q3);
    u.z = pack_bf16x2(q4, q5); u.w = pack_bf16x2(q6, q7);
  }
  ((uint4*)(A1 + (size_t)sg * H_))[threadIdx.x] = u;
}

// ---------------- fc1: barrier-free LDS-free MFMA GEMM + in-reg SwiGLU ------
// Block = 4 waves: wave = (mh = wave>>1, colg = wave&1). Wave owns m-chunks
// mh*8..mh*8+7 (128 rows) and cols {j0+16*colg..+15} for BOTH up and gate.
// B-frags built in registers from depth-2-prefetched global weight loads.
// No __syncthreads in the K-loop -> no vmcnt(0) drains; loads stay in flight.
__global__ __launch_bounds__(256) void fc1_kernel(
    const int* __restrict__ w1, const float* __restrict__ w1s,
    const float* __restrict__ is1v, const float* __restrict__ is2v,
    const __hip_bfloat16* __restrict__ A1, __hip_bfloat16* __restrict__ A2) {
  const int e = blockIdx.y;
  const int j0 = blockIdx.x * 32;
  const int tid = threadIdx.x;
  const int wave = tid >> 6, lane = tid & 63;
  const int lm = lane & 15, kq = lane >> 4;
  const int mh = wave >> 1, colg = wave & 1;
  const int cu = j0 + colg * 16 + lm;  // up column (gate column = cu + I_)
  const int* wpu = w1 + (size_t)e * H_ * N1_ + (size_t)(kq * 8) * N1_ + cu;
  const int* wpg = wpu + I_;
  const float* su = w1s + (size_t)e * (H_ / G_) * N1_ + cu;
  const float* sg = su + I_;
  const __hip_bfloat16* abase =
      A1 + (size_t)e * RPE * H_ + (size_t)(mh * 128 + lm) * H_ + kq * 8;

  f32x4 acc[8][2];
#pragma unroll
  for (int m = 0; m < 8; m++) {
    acc[m][0] = (f32x4){0.f, 0.f, 0.f, 0.f};
    acc[m][1] = (f32x4){0.f, 0.f, 0.f, 0.f};
  }

  int wu0[8], wu1[8], wg0[8], wg1[8];
  float sU0 = su[0], sU1 = sU0, sG0 = sg[0], sG1 = sG0;
#pragma unroll
  for (int i = 0; i < 8; i++) {
    wu0[i] = __builtin_nontemporal_load(wpu + (size_t)i * N1_);
    wg0[i] = __builtin_nontemporal_load(wpg + (size_t)i * N1_);
  }
#pragma unroll
  for (int i = 0; i < 8; i++) {
    wu1[i] = __builtin_nontemporal_load(wpu + (size_t)(32 + i) * N1_);
    wg1[i] = __builtin_nontemporal_load(wpg + (size_t)(32 + i) * N1_);
  }

  for (int ks = 0; ks < 64; ks++) {
    int wu2[8], wg2[8];
    float sU2 = sU1, sG2 = sG1;
    if (ks + 2 < 64) {
      if (((ks + 2) & 3) == 0) {
        sU2 = su[(size_t)((ks + 2) >> 2) * N1_];
        sG2 = sg[(size_t)((ks + 2) >> 2) * N1_];
      }
#pragma unroll
      for (int i = 0; i < 8; i++) {
        wu2[i] = __builtin_nontemporal_load(wpu + (size_t)((ks + 2) * 32 + i) * N1_);
        wg2[i] = __builtin_nontemporal_load(wpg + (size_t)((ks + 2) * 32 + i) * N1_);
      }
    }
    union { bf16x8 v; uint32_t u[4]; } bu, bg;
#pragma unroll
    for (int i = 0; i < 4; i++) {
      bu.u[i] = pack_bf16x2((float)wu0[2 * i] * sU0, (float)wu0[2 * i + 1] * sU0);
      bg.u[i] = pack_bf16x2((float)wg0[2 * i] * sG0, (float)wg0[2 * i + 1] * sG0);
    }
#pragma unroll
    for (int m = 0; m < 8; m++) {
      union { uint4 u; bf16x8 v; } a;
      a.u = *(const uint4*)(abase + (size_t)m * 16 * H_ + ks * 32);
      acc[m][0] = __builtin_amdgcn_mfma_f32_16x16x32_bf16(a.v, bu.v, acc[m][0], 0, 0, 0);
      acc[m][1] = __builtin_amdgcn_mfma_f32_16x16x32_bf16(a.v, bg.v, acc[m][1], 0, 0, 0);
    }
#pragma unroll
    for (int i = 0; i < 8; i++) { wu0[i] = wu1[i]; wu1[i] = wu2[i]; }
#pragma unroll
    for (int i = 0; i < 8; i++) { wg0[i] = wg1[i]; wg1[i] = wg2[i]; }
    sU0 = sU1; sU1 = sU2; sG0 = sG1; sG1 = sG2;
  }

  // epilogue: SwiGLU fully in registers (lane holds up & gate for same col)
  const float s1 = is1v[e], s2 = is2v[e];
#pragma unroll
  for (int m = 0; m < 8; m++) {
    int row = mh * 128 + m * 16 + kq * 4;
#pragma unroll
    for (int r = 0; r < 4; r++) {
      float up = acc[m][0][r] * s1;
      float gt = acc[m][1][r] * s1;
      float h = up * (gt / (1.0f + expf(-gt)));  // up * silu(gate)
      float q = fp8_qdq1(h / s2);
      A2[(size_t)(e * RPE + row + r) * I_ + cu] = __float2bfloat16(q);
    }
  }
}

// ---------------- fc2: same barrier-free structure, split-K x2, atomics -----
__global__ __launch_bounds__(256) void fc2_kernel(
    const int* __restrict__ w2, const float* __restrict__ w2s,
    const float* __restrict__ is2v, const int* __restrict__ cnt,
    const int* __restrict__ token_of, const float* __restrict__ gate_of,
    const __hip_bfloat16* __restrict__ A2, float* __restrict__ out) {
  const int e = blockIdx.y;
  const int n0 = blockIdx.x * 32;
  const int z = blockIdx.z;  // 2 slices * 88 k32-steps = 176 = I_/32
  const int tid = threadIdx.x;
  const int wave = tid >> 6, lane = tid & 63;
  const int lm = lane & 15, kq = lane >> 4;
  const int mh = wave >> 1, colg = wave & 1;
  const int nc = n0 + colg * 16 + lm;
  const int* wp = w2 + (size_t)e * I_ * H_ + (size_t)(z * 88 * 32 + kq * 8) * H_ + nc;
  const float* sp = w2s + (size_t)e * (I_ / G_) * H_ + (size_t)(z * 22) * H_ + nc;
  const __hip_bfloat16* abase =
      A2 + (size_t)e * RPE * I_ + (size_t)(mh * 128 + lm) * I_ + z * 88 * 32 + kq * 8;

  f32x4 acc[8];
#pragma unroll
  for (int m = 0; m < 8; m++) acc[m] = (f32x4){0.f, 0.f, 0.f, 0.f};

  int w0[8], w1r[8];
  float sc0 = sp[0], sc1 = sc0;
#pragma unroll
  for (int i = 0; i < 8; i++)
    w0[i] = __builtin_nontemporal_load(wp + (size_t)i * H_);
#pragma unroll
  for (int i = 0; i < 8; i++)
    w1r[i] = __builtin_nontemporal_load(wp + (size_t)(32 + i) * H_);

  for (int ks = 0; ks < 88; ks++) {
    int w2r[8];
    float sc2 = sc1;
    if (ks + 2 < 88) {
      if (((ks + 2) & 3) == 0) sc2 = sp[(size_t)((ks + 2) >> 2) * H_];
#pragma unroll
      for (int i = 0; i < 8; i++)
        w2r[i] = __builtin_nontemporal_load(wp + (size_t)((ks + 2) * 32 + i) * H_);
    }
    union { bf16x8 v; uint32_t u[4]; } bf;
#pragma unroll
    for (int i = 0; i < 4; i++)
      bf.u[i] = pack_bf16x2((float)w0[2 * i] * sc0, (float)w0[2 * i + 1] * sc0);
#pragma unroll
    for (int m = 0; m < 8; m++) {
      union { uint4 u; bf16x8 v; } a;
      a.u = *(const uint4*)(abase + (size_t)m * 16 * I_ + ks * 32);
      acc[m] = __builtin_amdgcn_mfma_f32_16x16x32_bf16(a.v, bf.v, acc[m], 0, 0, 0);
    }
#pragma unroll
    for (int i = 0; i < 8; i++) { w0[i] = w1r[i]; w1r[i] = w2r[i]; }
    sc0 = sc1; sc1 = sc2;
  }

  const float s2 = is2v[e];
  const int c_n = cnt[e];
#pragma unroll
  for (int m = 0; m < 8; m++) {
    int sl0 = mh * 128 + m * 16 + kq * 4;
#pragma unroll
    for (int r = 0; r < 4; r++) {
      int slot = sl0 + r;
      if (slot < c_n) {
        int t = token_of[e * RPE + slot];
        float gv = gate_of[e * RPE + slot] * s2;
        atomicAdd(out + (size_t)t * H_ + nc, acc[m][r] * gv);
      }
    }
  }
}

extern "C" void kernel_launch(void* const* d_in, const int* in_sizes, int n_in,
                              void* d_out, int out_size, void* d_ws, size_t ws_size,
                              hipStream_t stream) {
  const float* hidden = (const float*)d_in[0];
  const float* logits = (const float*)d_in[1];
  const int* w1 = (const int*)d_in[2];
  const int* w2 = (const int*)d_in[3];
  const float* w1s = (const float*)d_in[4];
  const float* w2s = (const float*)d_in[5];
  const float* is1 = (const float*)d_in[6];
  const float* is2 = (const float*)d_in[7];
  float* out = (float*)d_out;
  char* ws = (char*)d_ws;
  int* cnt = (int*)(ws + WS_CNT);
  int* token_of = (int*)(ws + WS_TOKEN);
  float* gate_of = (float*)(ws + WS_GATE);
  __hip_bfloat16* A1 = (__hip_bfloat16*)(ws + WS_A1);
  __hip_bfloat16* A2 = (__hip_bfloat16*)(ws + WS_A2);

  hipMemsetAsync(d_out, 0, (size_t)T_ * H_ * sizeof(float), stream);
  routing_kernel<<<1, 256, 0, stream>>>(logits, cnt, token_of, gate_of);
  gather_kernel<<<SLOTS, 256, 0, stream>>>(hidden, is1, cnt, token_of, A1);
  fc1_kernel<<<dim3(I_ / 32, E_), 256, 0, stream>>>(w1, w1s, is1, is2, A1, A2);
  fc2_kernel<<<dim3(H_ / 32, E_, 2), 256, 0, stream>>>(w2, w2s, is2, cnt, token_of,
                                                       gate_of, A2, out);
}

// Round 5
// 1663.163 us; speedup vs baseline: 1.2602x; 1.2602x over previous
//
#include <hip/hip_runtime.h>
#include <hip/hip_bf16.h>
#include <hip/hip_fp8.h>
#include <cstdint>
#include <cstddef>

// Problem constants (from reference)
#define E_ 8
#define H_ 2048
#define I_ 5632
#define N1_ (2 * I_)
#define G_ 128
#define T_ 256
#define RPE 256            // fixed rows per expert (= T_, exact worst case)
#define SLOTS (E_ * RPE)   // 2048

typedef __attribute__((ext_vector_type(4))) float f32x4;
typedef __attribute__((ext_vector_type(8))) __bf16 bf16x8;
typedef __attribute__((ext_vector_type(4))) int iv4;
typedef __attribute__((ext_vector_type(2))) int iv2;

// Workspace layout (bytes). Total ~31.5 MB.
#define WS_CNT 0
#define WS_TOKEN 64
#define WS_GATE (64 + SLOTS * 4)
#define WS_A1 32768                    // SLOTS * H_ bf16 = 8 MB
#define WS_A2 (WS_A1 + SLOTS * H_ * 2) // SLOTS * I_ bf16 = 23 MB

#define LPITCH 66  // LDS row pitch in ints: 64 cols + 2 pad -> 2-way banks (free)

__device__ __forceinline__ uint32_t pack_bf16x2(float a, float b) {
  union { float f; uint32_t u; } ua, ub;
  ua.f = a; ub.f = b;
  uint32_t ra = (ua.u + 0x7FFFu + ((ua.u >> 16) & 1u)) >> 16;         // RTNE bf16, low
  uint32_t rb = (ub.u + 0x7FFFu + ((ub.u >> 16) & 1u)) & 0xFFFF0000u; // high
  return ra | rb;
}

__device__ __forceinline__ uint32_t packsc2(float a, float b, float s) {
  union { __hip_bfloat162 h; uint32_t u; } cv;
  cv.h = __float22bfloat162_rn(make_float2(a * s, b * s));  // RTNE pair
  return cv.u;
}

__device__ __forceinline__ float fp8_qdq1(float x) {
  x = fminf(fmaxf(x, -448.0f), 448.0f);
  __hip_fp8_e4m3 q(x);  // OCP e4m3fn on gfx950
  return (float)q;
}

// ---------------- routing: softmax top-2 -> fixed-capacity slot lists -------
__global__ void routing_kernel(const float* __restrict__ logits,
                               int* __restrict__ cnt,
                               int* __restrict__ token_of, float* __restrict__ gate_of) {
  __shared__ int s_cnt[E_];
  int t = threadIdx.x;  // one thread per token; blockDim.x == T_ == 256
  if (t < E_) s_cnt[t] = 0;
  __syncthreads();
  float l[E_];
#pragma unroll
  for (int e = 0; e < E_; e++) l[e] = logits[t * E_ + e];
  int i0 = 0;
#pragma unroll
  for (int e = 1; e < E_; e++) if (l[e] > l[i0]) i0 = e;  // ties -> lower idx
  int i1 = (i0 == 0) ? 1 : 0;
#pragma unroll
  for (int e = 0; e < E_; e++) if (e != i0 && l[e] > l[i1]) i1 = e;
  float g0 = 1.0f / (1.0f + expf(l[i1] - l[i0]));  // renormalized top-2 gates
  float g1 = 1.0f - g0;
  int s0 = atomicAdd(&s_cnt[i0], 1);
  int s1 = atomicAdd(&s_cnt[i1], 1);
  token_of[i0 * RPE + s0] = t;  gate_of[i0 * RPE + s0] = g0;
  token_of[i1 * RPE + s1] = t;  gate_of[i1 * RPE + s1] = g1;
  __syncthreads();
  if (t < E_) cnt[t] = s_cnt[t];
  for (int idx = t; idx < SLOTS; idx += 256) {
    int e = idx >> 8, r = idx & (RPE - 1);
    if (r >= s_cnt[e]) { token_of[idx] = 0; gate_of[idx] = 0.0f; }
  }
}

// ---------------- gather + fp8 qdq -> A1 (bf16, zero-padded rows) -----------
__global__ void gather_kernel(const float* __restrict__ hidden,
                              const float* __restrict__ is1,
                              const int* __restrict__ cnt,
                              const int* __restrict__ token_of,
                              __hip_bfloat16* __restrict__ A1) {
  int sg = blockIdx.x;
  int e = sg >> 8, r = sg & (RPE - 1);
  bool pad = (r >= cnt[e]);
  uint4 u;
  if (pad) {
    u.x = u.y = u.z = u.w = 0u;
  } else {
    int t = token_of[sg];
    float s1 = is1[e];
    const float4* hp = (const float4*)(hidden + (size_t)t * H_ + threadIdx.x * 8);
    float4 x0 = hp[0], x1 = hp[1];
    u.x = pack_bf16x2(fp8_qdq1(x0.x / s1), fp8_qdq1(x0.y / s1));
    u.y = pack_bf16x2(fp8_qdq1(x0.z / s1), fp8_qdq1(x0.w / s1));
    u.z = pack_bf16x2(fp8_qdq1(x1.x / s1), fp8_qdq1(x1.y / s1));
    u.w = pack_bf16x2(fp8_qdq1(x1.z / s1), fp8_qdq1(x1.w / s1));
  }
  ((uint4*)(A1 + (size_t)sg * H_))[threadIdx.x] = u;
}

// ---------------- fc1: wide-load LDS-transpose MFMA GEMM + fused SwiGLU -----
// Block = 4 waves, M=256 (wave owns 64 rows), N = 32 up + 32 gate cols.
// Staging: 8x global_load_dwordx4 per lane per 32-K step (1 KB/instr wave-wide),
// raw int32 -> LDS [k][64n] (pitch 66). Frag build: 8 imm-offset ds_read_b32 +
// cvt+scale+pk_bf16 per 16-col frag (2-way banks, free). Double-buffered LDS,
// 1 barrier/step; staging loads issued early-iter -> drained a full iter later.
__global__ __launch_bounds__(256) void fc1_kernel(
    const int* __restrict__ w1, const float* __restrict__ w1s,
    const float* __restrict__ is1v, const float* __restrict__ is2v,
    const __hip_bfloat16* __restrict__ A1, __hip_bfloat16* __restrict__ A2) {
  __shared__ __align__(16) int Lw[2][32][LPITCH];  // 16.9 KB
  const int e = blockIdx.y;
  const int j0 = blockIdx.x * 32;
  const int tid = threadIdx.x;
  const int wave = tid >> 6, lane = tid & 63;
  const int lm = lane & 15, kq = lane >> 4;
  // staging mapping: per instr g (0..7): k-row = g*4 + skk, 4 cols at snn*4
  const int skk = lane >> 4;   // 0..3
  const int snn = lane & 15;   // 0..15 ; <8 -> up, >=8 -> gate
  const int scol = (snn < 8) ? (j0 + snn * 4) : (I_ + j0 + (snn - 8) * 4);
  const int* wbase = w1 + (size_t)e * H_ * N1_ + scol;
  // per-frag scale columns (f = 0,1 up ; 2,3 gate)
  const float* sp[4];
  sp[0] = w1s + (size_t)e * (H_ / G_) * N1_ + j0 + lm;
  sp[1] = sp[0] + 16;
  sp[2] = sp[0] + I_;
  sp[3] = sp[2] + 16;
  const __hip_bfloat16* abase =
      A1 + (size_t)e * RPE * H_ + (size_t)(wave * 64 + lm) * H_ + kq * 8;

  f32x4 acc[4][4];  // [m][f]
#pragma unroll
  for (int m = 0; m < 4; m++)
#pragma unroll
    for (int f = 0; f < 4; f++) acc[m][f] = (f32x4){0.f, 0.f, 0.f, 0.f};

  iv4 wr[8];
  // prologue: stage step 0, start loads for step 1
#pragma unroll
  for (int g = 0; g < 8; g++)
    wr[g] = __builtin_nontemporal_load(
        (const iv4*)(wbase + (size_t)(g * 4 + skk) * N1_));
#pragma unroll
  for (int g = 0; g < 8; g++) {
    int kl = g * 4 + skk;
    *(iv2*)&Lw[0][kl][snn * 4] = (iv2){wr[g].x, wr[g].y};
    *(iv2*)&Lw[0][kl][snn * 4 + 2] = (iv2){wr[g].z, wr[g].w};
  }
#pragma unroll
  for (int g = 0; g < 8; g++)
    wr[g] = __builtin_nontemporal_load(
        (const iv4*)(wbase + (size_t)(32 + g * 4 + skk) * N1_));

  float sc[4];
  for (int ks = 0; ks < 64; ks++) {
    const int buf = ks & 1;
    __syncthreads();  // buf ready; buf^1 free
    // stage step ks+1 (regs loaded last iter; vmcnt wait attaches here)
    if (ks + 1 < 64) {
#pragma unroll
      for (int g = 0; g < 8; g++) {
        int kl = g * 4 + skk;
        *(iv2*)&Lw[buf ^ 1][kl][snn * 4] = (iv2){wr[g].x, wr[g].y};
        *(iv2*)&Lw[buf ^ 1][kl][snn * 4 + 2] = (iv2){wr[g].z, wr[g].w};
      }
    }
    // issue loads for step ks+2 (clamped; drained at next iter's barrier)
    {
      int ksl = (ks + 2 < 64) ? (ks + 2) : 63;
#pragma unroll
      for (int g = 0; g < 8; g++)
        wr[g] = __builtin_nontemporal_load(
            (const iv4*)(wbase + (size_t)(ksl * 32 + g * 4 + skk) * N1_));
    }
    // A-frags for this step (L2/LLC-hot)
    uint4 af[4];
#pragma unroll
    for (int m = 0; m < 4; m++)
      af[m] = *(const uint4*)(abase + (size_t)(m * 16) * H_ + ks * 32);
    if ((ks & 3) == 0) {
      int g = ks >> 2;
#pragma unroll
      for (int f = 0; f < 4; f++) sc[f] = sp[f][(size_t)g * N1_];
    }
#pragma unroll
    for (int f = 0; f < 4; f++) {
      union { uint32_t u[4]; bf16x8 v; } bfr;
      const int nl = f * 16 + lm;
#pragma unroll
      for (int p = 0; p < 4; p++) {
        int wlo = Lw[buf][kq * 8 + 2 * p][nl];
        int whi = Lw[buf][kq * 8 + 2 * p + 1][nl];
        bfr.u[p] = packsc2((float)wlo, (float)whi, sc[f]);
      }
#pragma unroll
      for (int m = 0; m < 4; m++) {
        union { uint4 u; bf16x8 v; } au;
        au.u = af[m];
        acc[m][f] = __builtin_amdgcn_mfma_f32_16x16x32_bf16(au.v, bfr.v, acc[m][f], 0, 0, 0);
      }
    }
  }

  // epilogue: SwiGLU in registers (lane holds up f and gate f+2 for same col)
  const float s1 = is1v[e], s2 = is2v[e];
#pragma unroll
  for (int m = 0; m < 4; m++) {
    int row = wave * 64 + m * 16 + kq * 4;
#pragma unroll
    for (int r = 0; r < 4; r++) {
#pragma unroll
      for (int f = 0; f < 2; f++) {
        float up = acc[m][f][r] * s1;
        float gt = acc[m][f + 2][r] * s1;
        float h = up * (gt / (1.0f + expf(-gt)));  // up * silu(gate)
        float q = fp8_qdq1(h / s2);
        A2[(size_t)(e * RPE + row + r) * I_ + j0 + f * 16 + lm] = __float2bfloat16(q);
      }
    }
  }
}

// ---------------- fc2: same structure, N=64 out cols, split-K x4, atomics ---
__global__ __launch_bounds__(256) void fc2_kernel(
    const int* __restrict__ w2, const float* __restrict__ w2s,
    const float* __restrict__ is2v, const int* __restrict__ cnt,
    const int* __restrict__ token_of, const float* __restrict__ gate_of,
    const __hip_bfloat16* __restrict__ A2, float* __restrict__ out) {
  __shared__ __align__(16) int Lw[2][32][LPITCH];
  const int e = blockIdx.y;
  const int n0 = blockIdx.x * 64;
  const int z = blockIdx.z;  // 4 slices * 44 k32-steps = 176 = I_/32
  const int tid = threadIdx.x;
  const int wave = tid >> 6, lane = tid & 63;
  const int lm = lane & 15, kq = lane >> 4;
  const int skk = lane >> 4, snn = lane & 15;
  const int k0 = z * 44 * 32;
  const int* wbase = w2 + (size_t)e * I_ * H_ + (size_t)k0 * H_ + n0 + snn * 4;
  const float* sp[4];
  sp[0] = w2s + (size_t)e * (I_ / G_) * H_ + (size_t)(z * 11) * H_ + n0 + lm;
  sp[1] = sp[0] + 16;
  sp[2] = sp[0] + 32;
  sp[3] = sp[0] + 48;
  const __hip_bfloat16* abase =
      A2 + (size_t)e * RPE * I_ + (size_t)(wave * 64 + lm) * I_ + k0 + kq * 8;

  f32x4 acc[4][4];
#pragma unroll
  for (int m = 0; m < 4; m++)
#pragma unroll
    for (int f = 0; f < 4; f++) acc[m][f] = (f32x4){0.f, 0.f, 0.f, 0.f};

  iv4 wr[8];
#pragma unroll
  for (int g = 0; g < 8; g++)
    wr[g] = __builtin_nontemporal_load(
        (const iv4*)(wbase + (size_t)(g * 4 + skk) * H_));
#pragma unroll
  for (int g = 0; g < 8; g++) {
    int kl = g * 4 + skk;
    *(iv2*)&Lw[0][kl][snn * 4] = (iv2){wr[g].x, wr[g].y};
    *(iv2*)&Lw[0][kl][snn * 4 + 2] = (iv2){wr[g].z, wr[g].w};
  }
#pragma unroll
  for (int g = 0; g < 8; g++)
    wr[g] = __builtin_nontemporal_load(
        (const iv4*)(wbase + (size_t)(32 + g * 4 + skk) * H_));

  float sc[4];
  for (int ks = 0; ks < 44; ks++) {
    const int buf = ks & 1;
    __syncthreads();
    if (ks + 1 < 44) {
#pragma unroll
      for (int g = 0; g < 8; g++) {
        int kl = g * 4 + skk;
        *(iv2*)&Lw[buf ^ 1][kl][snn * 4] = (iv2){wr[g].x, wr[g].y};
        *(iv2*)&Lw[buf ^ 1][kl][snn * 4 + 2] = (iv2){wr[g].z, wr[g].w};
      }
    }
    {
      int ksl = (ks + 2 < 44) ? (ks + 2) : 43;
#pragma unroll
      for (int g = 0; g < 8; g++)
        wr[g] = __builtin_nontemporal_load(
            (const iv4*)(wbase + (size_t)(ksl * 32 + g * 4 + skk) * H_));
    }
    uint4 af[4];
#pragma unroll
    for (int m = 0; m < 4; m++)
      af[m] = *(const uint4*)(abase + (size_t)(m * 16) * I_ + ks * 32);
    if ((ks & 3) == 0) {
      int g = ks >> 2;
#pragma unroll
      for (int f = 0; f < 4; f++) sc[f] = sp[f][(size_t)g * H_];
    }
#pragma unroll
    for (int f = 0; f < 4; f++) {
      union { uint32_t u[4]; bf16x8 v; } bfr;
      const int nl = f * 16 + lm;
#pragma unroll
      for (int p = 0; p < 4; p++) {
        int wlo = Lw[buf][kq * 8 + 2 * p][nl];
        int whi = Lw[buf][kq * 8 + 2 * p + 1][nl];
        bfr.u[p] = packsc2((float)wlo, (float)whi, sc[f]);
      }
#pragma unroll
      for (int m = 0; m < 4; m++) {
        union { uint4 u; bf16x8 v; } au;
        au.u = af[m];
        acc[m][f] = __builtin_amdgcn_mfma_f32_16x16x32_bf16(au.v, bfr.v, acc[m][f], 0, 0, 0);
      }
    }
  }

  const float s2 = is2v[e];
  const int c_n = cnt[e];
#pragma unroll
  for (int m = 0; m < 4; m++) {
    int sl0 = wave * 64 + m * 16 + kq * 4;
#pragma unroll
    for (int r = 0; r < 4; r++) {
      int slot = sl0 + r;
      if (slot < c_n) {
        int t = token_of[e * RPE + slot];
        float gv = gate_of[e * RPE + slot] * s2;
#pragma unroll
        for (int f = 0; f < 4; f++)
          atomicAdd(out + (size_t)t * H_ + n0 + f * 16 + lm, acc[m][f][r] * gv);
      }
    }
  }
}

extern "C" void kernel_launch(void* const* d_in, const int* in_sizes, int n_in,
                              void* d_out, int out_size, void* d_ws, size_t ws_size,
                              hipStream_t stream) {
  const float* hidden = (const float*)d_in[0];
  const float* logits = (const float*)d_in[1];
  const int* w1 = (const int*)d_in[2];
  const int* w2 = (const int*)d_in[3];
  const float* w1s = (const float*)d_in[4];
  const float* w2s = (const float*)d_in[5];
  const float* is1 = (const float*)d_in[6];
  const float* is2 = (const float*)d_in[7];
  float* out = (float*)d_out;
  char* ws = (char*)d_ws;
  int* cnt = (int*)(ws + WS_CNT);
  int* token_of = (int*)(ws + WS_TOKEN);
  float* gate_of = (float*)(ws + WS_GATE);
  __hip_bfloat16* A1 = (__hip_bfloat16*)(ws + WS_A1);
  __hip_bfloat16* A2 = (__hip_bfloat16*)(ws + WS_A2);

  hipMemsetAsync(d_out, 0, (size_t)T_ * H_ * sizeof(float), stream);
  routing_kernel<<<1, 256, 0, stream>>>(logits, cnt, token_of, gate_of);
  gather_kernel<<<SLOTS, 256, 0, stream>>>(hidden, is1, cnt, token_of, A1);
  fc1_kernel<<<dim3(I_ / 32, E_), 256, 0, stream>>>(w1, w1s, is1, is2, A1, A2);
  fc2_kernel<<<dim3(H_ / 64, E_, 4), 256, 0, stream>>>(w2, w2s, is2, cnt, token_of,
                                                       gate_of, A2, out);
}